// Round 1
// baseline (137.586 us; speedup 1.0000x reference)
//
#include <hip/hip_runtime.h>

// Z: (2d+1, n+1) = (2049, 8193) fp32, alpha: (1,) fp32
// out = Z, except last row: out[2d, j] = Z[2d, j] + (alpha/n) * sum_{c<d} v[c]*(Z[c+d,j]-Z[c,j])
// where v[c] = sum_{j<n} Z[2d, j] * Z[c, j]

#define D  1024
#define N  8192
#define DD (2*D + 1)   // 2049
#define N1 (N + 1)     // 8193

// ---------------- Kernel A: full copy Z -> out (float4 grid-stride) ----------------
__global__ void copy_kernel(const float* __restrict__ Z, float* __restrict__ out, long total4) {
    long i = (long)blockIdx.x * blockDim.x + threadIdx.x;
    long stride = (long)gridDim.x * blockDim.x;
    const float4* __restrict__ src = (const float4*)Z;
    float4* __restrict__ dst = (float4*)out;
    for (; i < total4; i += stride) dst[i] = src[i];
    // tail: total elements 2049*8193 = 16787457 = 4*4196864 + 1
    if (blockIdx.x == 0 && threadIdx.x == 0) {
        long last = (long)DD * N1 - 1;
        out[last] = Z[last];
    }
}

// ---------------- Kernel B: v[c] = dot(Z[c, 0:N], Z[DD-1, 0:N]), one block per c ----------------
__global__ void dot_kernel(const float* __restrict__ Z, float* __restrict__ v) {
    const int c = blockIdx.x;
    const float* __restrict__ row = Z + (long)c * N1;
    const float* __restrict__ u   = Z + (long)(DD - 1) * N1;
    float acc = 0.f;
    for (int i = threadIdx.x; i < N; i += blockDim.x)
        acc += row[i] * u[i];
    // wave (64-lane) butterfly reduce
    for (int off = 32; off > 0; off >>= 1)
        acc += __shfl_down(acc, off, 64);
    __shared__ float smem[4];
    const int lane = threadIdx.x & 63;
    const int wid  = threadIdx.x >> 6;
    if (lane == 0) smem[wid] = acc;
    __syncthreads();
    if (threadIdx.x == 0)
        v[c] = smem[0] + smem[1] + smem[2] + smem[3];
}

// ---------------- Kernel C: last-row correction ----------------
// grid = (ceil(N1/256), 32). Each block: 256 columns x 32 c-values.
// Adds scale * sum_{c in split} v[c]*(Z[c+D,j]-Z[c,j]) onto out[DD-1, j] via atomicAdd.
__global__ void corr_kernel(const float* __restrict__ Z, const float* __restrict__ v,
                            const float* __restrict__ alpha, float* __restrict__ out) {
    const int j = blockIdx.x * blockDim.x + threadIdx.x;
    if (j >= N1) return;
    const int c0 = blockIdx.y * 32;
    float local = 0.f;
#pragma unroll 8
    for (int c = c0; c < c0 + 32; ++c) {
        const float vc = v[c];
        const float zp = Z[(long)(c + D) * N1 + j];
        const float zm = Z[(long)c * N1 + j];
        local += vc * (zp - zm);
    }
    const float scale = alpha[0] / (float)N;
    atomicAdd(&out[(long)(DD - 1) * N1 + j], scale * local);
}

extern "C" void kernel_launch(void* const* d_in, const int* in_sizes, int n_in,
                              void* d_out, int out_size, void* d_ws, size_t ws_size,
                              hipStream_t stream) {
    const float* Z     = (const float*)d_in[0];
    const float* alpha = (const float*)d_in[1];
    float* out = (float*)d_out;
    float* v   = (float*)d_ws;   // D floats = 4 KB

    const long total4 = ((long)DD * N1) / 4;  // 4196864
    copy_kernel<<<4096, 256, 0, stream>>>(Z, out, total4);
    dot_kernel<<<D, 256, 0, stream>>>(Z, v);
    corr_kernel<<<dim3((N1 + 255) / 256, 32), 256, 0, stream>>>(Z, v, alpha, out);
}

// Round 3
// 129.411 us; speedup vs baseline: 1.0632x; 1.0632x over previous
//
#include <hip/hip_runtime.h>

// Z: (2049, 8193) fp32, alpha: (1,) fp32.
// out = Z, except last row: out[2048, j] += (alpha/N) * sum_{c<D} v[c]*(Z[c+D,j]-Z[c,j])
// where v[c] = sum_{j<N} Z[2048, j] * Z[c, j]

#define D     1024
#define N     8192
#define DD    2049
#define N1    8193
#define NDOT  1024            // blocks 0..1023: one dot-row each
#define NCOPY 3584            // blocks 1024..4607: flat float4 copy
#define TOTAL4 4196864L       // (2049*8193)/4, remainder 1 element tail

typedef float f32x4 __attribute__((ext_vector_type(4)));  // clang vector: valid for nontemporal builtins

// ---------------- Kernel 1: fused copy + dot ----------------
__global__ void fused_copy_dot(const float* __restrict__ Z, float* __restrict__ out,
                               float* __restrict__ v) {
    const int b = blockIdx.x;
    if (b < NDOT) {
        // v[c] = dot(Z[c, 0:N], Z[2048, 0:N])
        const int c = b;
        const float* __restrict__ row = Z + (long)c * N1;
        const float* __restrict__ u   = Z + (long)(DD - 1) * N1;
        float acc = 0.f;
        for (int i = threadIdx.x; i < N; i += 256)
            acc += row[i] * u[i];
        #pragma unroll
        for (int off = 32; off > 0; off >>= 1)
            acc += __shfl_down(acc, off, 64);
        __shared__ float smem[4];
        const int lane = threadIdx.x & 63;
        const int wid  = threadIdx.x >> 6;
        if (lane == 0) smem[wid] = acc;
        __syncthreads();
        if (threadIdx.x == 0)
            v[c] = smem[0] + smem[1] + smem[2] + smem[3];
        // odd tail element of the flat copy (2049*8193 = 4*TOTAL4 + 1)
        if (c == 0 && threadIdx.x == 64) {
            const long last = (long)DD * N1 - 1;
            out[last] = Z[last];
        }
    } else {
        // flat float4 copy with non-temporal stores (keep Z resident in L3 for corr pass)
        long i = (long)(b - NDOT) * 256 + threadIdx.x;
        const long stride = (long)NCOPY * 256;
        const f32x4* __restrict__ src = (const f32x4*)Z;
        f32x4*       __restrict__ dst = (f32x4*)out;
        for (; i < TOTAL4; i += stride) {
            f32x4 val = src[i];
            __builtin_nontemporal_store(val, &dst[i]);
        }
    }
}

// ---------------- Kernel 2: last-row correction ----------------
// grid = (33, 32): 256 columns x 32 c-values per block; one atomicAdd per thread.
__global__ void corr_kernel(const float* __restrict__ Z, const float* __restrict__ v,
                            const float* __restrict__ alpha, float* __restrict__ out) {
    const int j = blockIdx.x * 256 + threadIdx.x;
    if (j >= N1) return;
    const int c0 = blockIdx.y * 32;
    float local = 0.f;
    #pragma unroll 8
    for (int cc = 0; cc < 32; ++cc) {
        const int c = c0 + cc;
        const float zp = Z[(long)(c + D) * N1 + j];
        const float zm = Z[(long)c * N1 + j];
        local += v[c] * (zp - zm);
    }
    const float scale = alpha[0] / (float)N;
    atomicAdd(&out[(long)(DD - 1) * N1 + j], scale * local);
}

extern "C" void kernel_launch(void* const* d_in, const int* in_sizes, int n_in,
                              void* d_out, int out_size, void* d_ws, size_t ws_size,
                              hipStream_t stream) {
    const float* Z     = (const float*)d_in[0];
    const float* alpha = (const float*)d_in[1];
    float* out = (float*)d_out;
    float* v   = (float*)d_ws;   // D floats = 4 KB scratch

    fused_copy_dot<<<NDOT + NCOPY, 256, 0, stream>>>(Z, out, v);
    corr_kernel<<<dim3((N1 + 255) / 256, 32), 256, 0, stream>>>(Z, v, alpha, out);
}